// Round 9
// baseline (236.727 us; speedup 1.0000x reference)
//
#include <hip/hip_runtime.h>
#include <hip/hip_fp16.h>
#include <math.h>

constexpr float NEG_SLOPE = 0.2f;
constexpr float BN_EPS_C = 1e-5f;

using half8 = __attribute__((ext_vector_type(8))) _Float16;
using f32x4 = __attribute__((ext_vector_type(4))) float;

// ================= weight fp16 pre-conversion =================

__global__ void cvt_w_kernel(const float* __restrict__ W0, const float* __restrict__ W1,
                             const float* __restrict__ W2,
                             __half* __restrict__ W0h, __half* __restrict__ W1h,
                             __half* __restrict__ W2h) {
    int i = blockIdx.x * blockDim.x + threadIdx.x;
    if (i < 16384) {
        W0h[i] = __float2half(W0[i]);
        W1h[i] = __float2half(W1[i]);
    }
    if (i < 6144) W2h[i] = __float2half(i < 5120 ? W2[i] : 0.f);  // pad rows 40..47 = 0
}

// ================= CSR build: LDS-binned two-level counting sort =================

__global__ __launch_bounds__(256)
void bucket_hist_kernel(const int* __restrict__ ei, int* __restrict__ bucket_count,
                        int E, int N) {
    __shared__ int h[256];
    int t = threadIdx.x;
    h[t] = 0;
    __syncthreads();
    int base = blockIdx.x * 4096;
    int ET = E + N;
#pragma unroll
    for (int q = 0; q < 16; ++q) {
        int i = base + q * 256 + t;
        if (i < ET) {
            int d = (i < E) ? ei[E + i] : (i - E);
            atomicAdd(&h[d >> 8], 1);
        }
    }
    __syncthreads();
    if (h[t] > 0) atomicAdd(&bucket_count[t], h[t]);
}

__global__ __launch_bounds__(256)
void bucket_scan_kernel(const int* __restrict__ bucket_count, int* __restrict__ bucket_ptr,
                        int* __restrict__ gcursor, int* __restrict__ row_ptr,
                        int N, int ET) {
    __shared__ int s[256];
    int t = threadIdx.x;
    int c = bucket_count[t];
    s[t] = c;
    __syncthreads();
    for (int off = 1; off < 256; off <<= 1) {
        int v = (t >= off) ? s[t - off] : 0;
        __syncthreads();
        s[t] += v;
        __syncthreads();
    }
    int excl = s[t] - c;
    bucket_ptr[t] = excl;
    gcursor[t] = excl;
    if (t == 255) {
        bucket_ptr[256] = s[255];
        row_ptr[N] = ET;
    }
}

__global__ __launch_bounds__(256)
void bucket_bin_kernel(const int* __restrict__ ei, int* __restrict__ gcursor,
                       int2* __restrict__ tmp, int E, int N) {
    __shared__ int2 bins[4096];
    __shared__ int lcount[256];
    __shared__ int lofs[256];
    __shared__ int lbase[256];
    __shared__ int lcur[256];
    int t = threadIdx.x;
    lcount[t] = 0;
    __syncthreads();
    int base = blockIdx.x * 4096;
    int ET = E + N;
    int2 pr[16];
#pragma unroll
    for (int q = 0; q < 16; ++q) {
        int i = base + q * 256 + t;
        pr[q] = make_int2(-1, -1);
        if (i < ET) {
            int s, d;
            if (i < E) { s = ei[i]; d = ei[E + i]; }
            else       { s = i - E; d = s; }
            pr[q] = make_int2(d, s);
            atomicAdd(&lcount[d >> 8], 1);
        }
    }
    __syncthreads();
    {
        int c = lcount[t];
        lofs[t] = c;
        __syncthreads();
        for (int off = 1; off < 256; off <<= 1) {
            int v = (t >= off) ? lofs[t - off] : 0;
            __syncthreads();
            lofs[t] += v;
            __syncthreads();
        }
        int excl = lofs[t] - c;
        __syncthreads();
        lofs[t] = excl;
        lcur[t] = excl;
        if (c > 0) lbase[t] = atomicAdd(&gcursor[t], c);
    }
    __syncthreads();
#pragma unroll
    for (int q = 0; q < 16; ++q) {
        if (pr[q].x >= 0) {
            int b = pr[q].x >> 8;
            int p = atomicAdd(&lcur[b], 1);
            bins[p] = pr[q];
        }
    }
    __syncthreads();
    int total = min(4096, ET - base);
    for (int p = t; p < total; p += 256) {
        int2 e = bins[p];
        int b = e.x >> 8;
        tmp[lbase[b] + (p - lofs[b])] = e;
    }
}

__global__ __launch_bounds__(256)
void fine_scatter_kernel(const int2* __restrict__ tmp, const int* __restrict__ bucket_ptr,
                         int* __restrict__ row_ptr, int* __restrict__ srcs, int N) {
    __shared__ int hist[256];
    __shared__ int scanb[256];
    __shared__ int cur[256];
    int b = blockIdx.x, t = threadIdx.x;
    int base = bucket_ptr[b];
    int cnt = bucket_ptr[b + 1] - base;
    int n0 = b << 8;
    hist[t] = 0;
    __syncthreads();
    for (int p = t; p < cnt; p += 256)
        atomicAdd(&hist[tmp[base + p].x - n0], 1);
    __syncthreads();
    int c = hist[t];
    scanb[t] = c;
    __syncthreads();
    for (int off = 1; off < 256; off <<= 1) {
        int v = (t >= off) ? scanb[t - off] : 0;
        __syncthreads();
        scanb[t] += v;
        __syncthreads();
    }
    int excl = scanb[t] - c;
    cur[t] = excl;
    if (n0 + t < N) row_ptr[n0 + t] = base + excl;
    __syncthreads();
    for (int p = t; p < cnt; p += 256) {
        int2 e = tmp[base + p];
        int pos = atomicAdd(&cur[e.x - n0], 1);
        srcs[base + pos] = e.y;
    }
}

// ---------------- MFMA GEMM 128 (no LDS): h(fp16) = X @ W^T + alphas ----------------
// Block = 256 threads = 4 waves; block covers 64 rows. Wave w: A-rows 16w+lr.
// B (fp16 weights, L1/L2-resident) loaded directly as half8 fragments.
// C/D: col=lane&15, row=(lane>>4)*4+reg (verified passing rounds 6-8).

template<bool AHALF>
__global__ __launch_bounds__(256)
void gemm128_mfma_kernel(const void* __restrict__ Xv, const __half* __restrict__ W16,
                         const float* __restrict__ a_src, const float* __restrict__ a_dst,
                         __half* __restrict__ hp, float* __restrict__ asrc,
                         float* __restrict__ adst, int N) {
    const int t = threadIdx.x;
    const int l  = t & 63;
    const int w  = t >> 6;   // 0..3
    const int lr = l & 15;
    const int lg = l >> 4;   // 0..3
    const int n0 = blockIdx.x * 64;
    const int rowA = n0 + 16 * w + lr;
    const bool rokA = rowA < N;

    f32x4 acc[8];
#pragma unroll
    for (int tt = 0; tt < 8; ++tt) acc[tt] = (f32x4){0.f, 0.f, 0.f, 0.f};

#pragma unroll
    for (int ks = 0; ks < 4; ++ks) {
        half8 a;
        if (rokA) {
            if constexpr (AHALF) {
                const __half* X = (const __half*)Xv;
                a = *reinterpret_cast<const half8*>(&X[(size_t)rowA * 128 + 8 * lg + 32 * ks]);
            } else {
                const float* X = (const float*)Xv;
                const float* p = &X[(size_t)rowA * 128 + 8 * lg + 32 * ks];
                float4 v0 = *reinterpret_cast<const float4*>(p);
                float4 v1 = *reinterpret_cast<const float4*>(p + 4);
                a[0] = (_Float16)v0.x; a[1] = (_Float16)v0.y;
                a[2] = (_Float16)v0.z; a[3] = (_Float16)v0.w;
                a[4] = (_Float16)v1.x; a[5] = (_Float16)v1.y;
                a[6] = (_Float16)v1.z; a[7] = (_Float16)v1.w;
            }
        } else {
#pragma unroll
            for (int q = 0; q < 8; ++q) a[q] = (_Float16)0.f;
        }
#pragma unroll
        for (int tt = 0; tt < 8; ++tt) {
            half8 b = *reinterpret_cast<const half8*>(
                &W16[(size_t)(16 * tt + lr) * 128 + 8 * lg + 32 * ks]);
            acc[tt] = __builtin_amdgcn_mfma_f32_16x16x32_f16(a, b, acc[tt], 0, 0, 0);
        }
    }

    float av[8], bv[8];
#pragma unroll
    for (int tt = 0; tt < 8; ++tt) {
        av[tt] = a_src[16 * tt + lr];
        bv[tt] = a_dst[16 * tt + lr];
    }
#pragma unroll
    for (int reg = 0; reg < 4; ++reg) {
        int gr = n0 + 16 * w + 4 * lg + reg;
        bool ok = gr < N;
        if (ok) {
#pragma unroll
            for (int tt = 0; tt < 8; ++tt)
                hp[(size_t)gr * 128 + 16 * tt + lr] = __float2half(acc[tt][reg]);
        }
#pragma unroll
        for (int tt = 0; tt < 8; ++tt) {
            float p = acc[tt][reg] * av[tt];
            float q = acc[tt][reg] * bv[tt];
#pragma unroll
            for (int off = 1; off < 16; off <<= 1) {
                p += __shfl_xor(p, off, 16);
                q += __shfl_xor(q, off, 16);
            }
            if (ok && lr == tt) {
                asrc[(size_t)gr * 8 + tt] = p;
                adst[(size_t)gr * 8 + tt] = q;
            }
        }
    }
}

// ---------------- MFMA GEMM 40 (no LDS): h2(fp16) = feat @ W2^T + alphas ----------------
// W2h padded to 48x128 (rows 40..47 zero).  A = fp16 feat, direct half8 loads.

__global__ __launch_bounds__(256)
void gemm40_mfma_kernel(const __half* __restrict__ X, const __half* __restrict__ W16,
                        const float* __restrict__ a_src, const float* __restrict__ a_dst,
                        __half* __restrict__ hp, float* __restrict__ asrc,
                        float* __restrict__ adst, int N) {
    const int t = threadIdx.x;
    const int l  = t & 63;
    const int w  = t >> 6;
    const int lr = l & 15;
    const int lg = l >> 4;
    const int n0 = blockIdx.x * 64;
    const int rowA = n0 + 16 * w + lr;
    const bool rokA = rowA < N;

    f32x4 acc[3];
#pragma unroll
    for (int tt = 0; tt < 3; ++tt) acc[tt] = (f32x4){0.f, 0.f, 0.f, 0.f};

#pragma unroll
    for (int ks = 0; ks < 4; ++ks) {
        half8 a;
        if (rokA) {
            a = *reinterpret_cast<const half8*>(&X[(size_t)rowA * 128 + 8 * lg + 32 * ks]);
        } else {
#pragma unroll
            for (int q = 0; q < 8; ++q) a[q] = (_Float16)0.f;
        }
#pragma unroll
        for (int tt = 0; tt < 3; ++tt) {
            half8 b = *reinterpret_cast<const half8*>(
                &W16[(size_t)(16 * tt + lr) * 128 + 8 * lg + 32 * ks]);
            acc[tt] = __builtin_amdgcn_mfma_f32_16x16x32_f16(a, b, acc[tt], 0, 0, 0);
        }
    }

    float av[3], bv[3];
#pragma unroll
    for (int tt = 0; tt < 3; ++tt) {
        int j = 16 * tt + lr;
        av[tt] = (j < 40) ? a_src[j] : 0.f;
        bv[tt] = (j < 40) ? a_dst[j] : 0.f;
    }
#pragma unroll
    for (int reg = 0; reg < 4; ++reg) {
        int gr = n0 + 16 * w + 4 * lg + reg;
        bool ok = gr < N;
        float p = 0.f, q = 0.f;
#pragma unroll
        for (int tt = 0; tt < 3; ++tt) {
            int j = 16 * tt + lr;
            if (ok && j < 40) hp[(size_t)gr * 40 + j] = __float2half(acc[tt][reg]);
            p += acc[tt][reg] * av[tt];
            q += acc[tt][reg] * bv[tt];
        }
#pragma unroll
        for (int off = 1; off < 16; off <<= 1) {
            p += __shfl_xor(p, off, 16);
            q += __shfl_xor(q, off, 16);
        }
        if (ok && lr == 0) {
            asrc[gr] = p;
            adst[gr] = q;
        }
    }
}

// ---------------- fused message + softmax, F=128, H=8, fp16 out ----------------
// 32 lanes/node; 16 lanes/edge, up to 4 edges in flight (2 per half).

__global__ __launch_bounds__(256)
void message128_kernel(const uint4* __restrict__ hh4, const int* __restrict__ row_ptr,
                       const int* __restrict__ srcs,
                       const float* __restrict__ asrc, const float* __restrict__ adst,
                       const float* __restrict__ bias,
                       const float* __restrict__ bn_g, const float* __restrict__ bn_b,
                       const float* __restrict__ bn_m, const float* __restrict__ bn_v,
                       __half* __restrict__ out16, int N) {
    int node = blockIdx.x * 8 + (threadIdx.x >> 5);
    if (node >= N) return;
    int tc = threadIdx.x & 31;
    int half_id = tc >> 4;
    int cl = tc & 15;
    int hd = cl >> 1;
    int beg = row_ptr[node], end = row_ptr[node + 1];
    float ad = adst[(size_t)node * 8 + hd];
    float ssum = 0.f;
    float acc[8];
#pragma unroll
    for (int q = 0; q < 8; ++q) acc[q] = 0.f;

    int j = beg;
    for (; j + 4 <= end; j += 4) {
        int sA = srcs[j + half_id];
        int sB = srcs[j + 2 + half_id];
        uint4 uA = hh4[(size_t)sA * 16 + cl];
        uint4 uB = hh4[(size_t)sB * 16 + cl];
        float eA = asrc[(size_t)sA * 8 + hd] + ad;
        float eB = asrc[(size_t)sB * 8 + hd] + ad;
        eA = (eA > 0.f) ? eA : NEG_SLOPE * eA;
        eB = (eB > 0.f) ? eB : NEG_SLOPE * eB;
        float wA = __expf(eA);
        float wB = __expf(eB);
        ssum += wA + wB;
        float2 a0 = __half22float2(*reinterpret_cast<const __half2*>(&uA.x));
        float2 a1 = __half22float2(*reinterpret_cast<const __half2*>(&uA.y));
        float2 a2 = __half22float2(*reinterpret_cast<const __half2*>(&uA.z));
        float2 a3 = __half22float2(*reinterpret_cast<const __half2*>(&uA.w));
        float2 b0 = __half22float2(*reinterpret_cast<const __half2*>(&uB.x));
        float2 b1 = __half22float2(*reinterpret_cast<const __half2*>(&uB.y));
        float2 b2 = __half22float2(*reinterpret_cast<const __half2*>(&uB.z));
        float2 b3 = __half22float2(*reinterpret_cast<const __half2*>(&uB.w));
        acc[0] += wA * a0.x + wB * b0.x; acc[1] += wA * a0.y + wB * b0.y;
        acc[2] += wA * a1.x + wB * b1.x; acc[3] += wA * a1.y + wB * b1.y;
        acc[4] += wA * a2.x + wB * b2.x; acc[5] += wA * a2.y + wB * b2.y;
        acc[6] += wA * a3.x + wB * b3.x; acc[7] += wA * a3.y + wB * b3.y;
    }
    for (; j + 2 <= end; j += 2) {
        int s = srcs[j + half_id];
        uint4 u = hh4[(size_t)s * 16 + cl];
        float e = asrc[(size_t)s * 8 + hd] + ad;
        e = (e > 0.f) ? e : NEG_SLOPE * e;
        float wgt = __expf(e);
        ssum += wgt;
        float2 f0 = __half22float2(*reinterpret_cast<const __half2*>(&u.x));
        float2 f1 = __half22float2(*reinterpret_cast<const __half2*>(&u.y));
        float2 f2 = __half22float2(*reinterpret_cast<const __half2*>(&u.z));
        float2 f3 = __half22float2(*reinterpret_cast<const __half2*>(&u.w));
        acc[0] += wgt * f0.x; acc[1] += wgt * f0.y;
        acc[2] += wgt * f1.x; acc[3] += wgt * f1.y;
        acc[4] += wgt * f2.x; acc[5] += wgt * f2.y;
        acc[6] += wgt * f3.x; acc[7] += wgt * f3.y;
    }
    if (j < end && half_id == 0) {
        int s = srcs[j];
        uint4 u = hh4[(size_t)s * 16 + cl];
        float e = asrc[(size_t)s * 8 + hd] + ad;
        e = (e > 0.f) ? e : NEG_SLOPE * e;
        float wgt = __expf(e);
        ssum += wgt;
        float2 f0 = __half22float2(*reinterpret_cast<const __half2*>(&u.x));
        float2 f1 = __half22float2(*reinterpret_cast<const __half2*>(&u.y));
        float2 f2 = __half22float2(*reinterpret_cast<const __half2*>(&u.z));
        float2 f3 = __half22float2(*reinterpret_cast<const __half2*>(&u.w));
        acc[0] += wgt * f0.x; acc[1] += wgt * f0.y;
        acc[2] += wgt * f1.x; acc[3] += wgt * f1.y;
        acc[4] += wgt * f2.x; acc[5] += wgt * f2.y;
        acc[6] += wgt * f3.x; acc[7] += wgt * f3.y;
    }
    ssum += __shfl_xor(ssum, 16);
#pragma unroll
    for (int q = 0; q < 8; ++q) acc[q] += __shfl_xor(acc[q], 16);

    if (half_id == 0) {
        float inv = 1.0f / (ssum + 1e-16f);
        int c = cl * 8;
        float r[8];
#pragma unroll
        for (int pp = 0; pp < 2; ++pp) {
            int cc = c + 4 * pp;
            float4 bi = *reinterpret_cast<const float4*>(&bias[cc]);
            float4 g  = *reinterpret_cast<const float4*>(&bn_g[cc]);
            float4 bb = *reinterpret_cast<const float4*>(&bn_b[cc]);
            float4 mm = *reinterpret_cast<const float4*>(&bn_m[cc]);
            float4 vv = *reinterpret_cast<const float4*>(&bn_v[cc]);
            r[4 * pp + 0] = (acc[4 * pp + 0] * inv + bi.x - mm.x) * rsqrtf(vv.x + BN_EPS_C) * g.x + bb.x;
            r[4 * pp + 1] = (acc[4 * pp + 1] * inv + bi.y - mm.y) * rsqrtf(vv.y + BN_EPS_C) * g.y + bb.y;
            r[4 * pp + 2] = (acc[4 * pp + 2] * inv + bi.z - mm.z) * rsqrtf(vv.z + BN_EPS_C) * g.z + bb.z;
            r[4 * pp + 3] = (acc[4 * pp + 3] * inv + bi.w - mm.w) * rsqrtf(vv.w + BN_EPS_C) * g.w + bb.w;
        }
        half8 o;
#pragma unroll
        for (int q = 0; q < 8; ++q) {
            float rv = (r[q] > 0.f) ? r[q] : expm1f(r[q]);
            o[q] = (_Float16)rv;
        }
        *reinterpret_cast<half8*>(&out16[(size_t)node * 128 + c]) = o;
    }
}

// ---------------- fused message + softmax, F=40, H=1, fp16 gather ----------------

__global__ __launch_bounds__(256)
void message40_kernel(const uint2* __restrict__ hh2, const int* __restrict__ row_ptr,
                      const int* __restrict__ srcs,
                      const float* __restrict__ asrc, const float* __restrict__ adst,
                      const float* __restrict__ b2, float* __restrict__ out, int N) {
    int node = blockIdx.x * 16 + (threadIdx.x >> 4);
    if (node >= N) return;
    int tc = threadIdx.x & 15;
    int beg = row_ptr[node], end = row_ptr[node + 1];
    float ad = adst[node];
    float ssum = 0.f;
    float4 acc = make_float4(0.f, 0.f, 0.f, 0.f);
    int j = beg;
    for (; j + 2 <= end; j += 2) {
        int s0 = srcs[j];
        int s1 = srcs[j + 1];
        uint2 u0 = make_uint2(0u, 0u), u1 = make_uint2(0u, 0u);
        if (tc < 10) {
            u0 = hh2[(size_t)s0 * 10 + tc];
            u1 = hh2[(size_t)s1 * 10 + tc];
        }
        float e0 = asrc[s0] + ad;
        float e1 = asrc[s1] + ad;
        e0 = (e0 > 0.f) ? e0 : NEG_SLOPE * e0;
        e1 = (e1 > 0.f) ? e1 : NEG_SLOPE * e1;
        float w0 = __expf(e0);
        float w1 = __expf(e1);
        ssum += w0 + w1;
        float2 a0 = __half22float2(*reinterpret_cast<const __half2*>(&u0.x));
        float2 b0 = __half22float2(*reinterpret_cast<const __half2*>(&u0.y));
        float2 a1 = __half22float2(*reinterpret_cast<const __half2*>(&u1.x));
        float2 b1 = __half22float2(*reinterpret_cast<const __half2*>(&u1.y));
        acc.x += w0 * a0.x + w1 * a1.x;
        acc.y += w0 * a0.y + w1 * a1.y;
        acc.z += w0 * b0.x + w1 * b1.x;
        acc.w += w0 * b0.y + w1 * b1.y;
    }
    if (j < end) {
        int s0 = srcs[j];
        uint2 u0 = make_uint2(0u, 0u);
        if (tc < 10) u0 = hh2[(size_t)s0 * 10 + tc];
        float e0 = asrc[s0] + ad;
        e0 = (e0 > 0.f) ? e0 : NEG_SLOPE * e0;
        float w0 = __expf(e0);
        ssum += w0;
        float2 a0 = __half22float2(*reinterpret_cast<const __half2*>(&u0.x));
        float2 b0 = __half22float2(*reinterpret_cast<const __half2*>(&u0.y));
        acc.x += w0 * a0.x;
        acc.y += w0 * a0.y;
        acc.z += w0 * b0.x;
        acc.w += w0 * b0.y;
    }
    if (tc < 10) {
        float inv = 1.0f / (ssum + 1e-16f);
        int c = tc * 4;
        float4 bi = *reinterpret_cast<const float4*>(&b2[c]);
        *reinterpret_cast<float4*>(&out[(size_t)node * 40 + c]) =
            make_float4(acc.x * inv + bi.x, acc.y * inv + bi.y,
                        acc.z * inv + bi.z, acc.w * inv + bi.w);
    }
}

// ---------------- launcher ----------------

static inline char* align256(char* p) {
    return (char*)(((uintptr_t)p + 255) & ~(uintptr_t)255);
}

extern "C" void kernel_launch(void* const* d_in, const int* in_sizes, int n_in,
                              void* d_out, int out_size, void* d_ws, size_t ws_size,
                              hipStream_t stream) {
    const float* x   = (const float*)d_in[0];
    const int*   ei  = (const int*)d_in[1];
    const float* W0  = (const float*)d_in[2];
    const float* as0 = (const float*)d_in[3];
    const float* ad0 = (const float*)d_in[4];
    const float* b0  = (const float*)d_in[5];
    const float* g0  = (const float*)d_in[6];
    const float* bb0 = (const float*)d_in[7];
    const float* m0  = (const float*)d_in[8];
    const float* v0  = (const float*)d_in[9];
    const float* W1  = (const float*)d_in[10];
    const float* as1 = (const float*)d_in[11];
    const float* ad1 = (const float*)d_in[12];
    const float* b1  = (const float*)d_in[13];
    const float* g1  = (const float*)d_in[14];
    const float* bb1 = (const float*)d_in[15];
    const float* m1  = (const float*)d_in[16];
    const float* v1  = (const float*)d_in[17];
    const float* W2  = (const float*)d_in[18];
    const float* as2 = (const float*)d_in[19];
    const float* ad2 = (const float*)d_in[20];
    const float* b2  = (const float*)d_in[21];

    const int N  = in_sizes[0] / 128;
    const int E  = in_sizes[1] / 2;
    const int ET = E + N;
    const int NBUK = (N + 255) >> 8;
    const int NEB  = (ET + 4095) / 4096;

    char* wsp = (char*)d_ws;
    int* bucket_count = (int*)wsp;  wsp = align256(wsp + 256 * 4);
    int* bucket_ptr   = (int*)wsp;  wsp = align256(wsp + 257 * 4);
    int* gcursor      = (int*)wsp;  wsp = align256(wsp + 256 * 4);
    int* row_ptr      = (int*)wsp;  wsp = align256(wsp + (size_t)(N + 1) * 4);
    int2* tmp         = (int2*)wsp; wsp = align256(wsp + (size_t)ET * 8);
    int* srcs         = (int*)wsp;  wsp = align256(wsp + (size_t)ET * 4);
    __half* hh        = (__half*)wsp; wsp = align256(wsp + (size_t)N * 128 * 2);
    __half* h2        = (__half*)wsp; wsp = align256(wsp + (size_t)N * 40 * 2);
    __half* feat      = (__half*)wsp; wsp = align256(wsp + (size_t)N * 128 * 2);
    float* asr        = (float*)wsp;  wsp = align256(wsp + (size_t)N * 8 * 4);
    float* adt        = (float*)wsp;  wsp = align256(wsp + (size_t)N * 8 * 4);
    __half* W0h       = (__half*)wsp; wsp = align256(wsp + 16384 * 2);
    __half* W1h       = (__half*)wsp; wsp = align256(wsp + 16384 * 2);
    __half* W2h       = (__half*)wsp; wsp = align256(wsp + 6144 * 2);

    // weight fp16 pre-conversion (once)
    cvt_w_kernel<<<64, 256, 0, stream>>>(W0, W1, W2, W0h, W1h, W2h);

    // CSR build (LDS-binned two-level counting sort)
    hipMemsetAsync(bucket_count, 0, 256 * 4, stream);
    bucket_hist_kernel<<<NEB, 256, 0, stream>>>(ei, bucket_count, E, N);
    bucket_scan_kernel<<<1, 256, 0, stream>>>(bucket_count, bucket_ptr, gcursor, row_ptr, N, ET);
    bucket_bin_kernel<<<NEB, 256, 0, stream>>>(ei, gcursor, tmp, E, N);
    fine_scatter_kernel<<<NBUK, 256, 0, stream>>>(tmp, bucket_ptr, row_ptr, srcs, N);

    const int g64 = (N + 63) / 64;

    // layer 0: x (fp32) -> feat (fp16)
    gemm128_mfma_kernel<false><<<g64, 256, 0, stream>>>(x, W0h, as0, ad0, hh, asr, adt, N);
    message128_kernel<<<(N + 7) / 8, 256, 0, stream>>>((const uint4*)hh, row_ptr, srcs, asr, adt,
                                                       b0, g0, bb0, m0, v0, feat, N);
    // layer 1: feat (fp16) -> feat (fp16)
    gemm128_mfma_kernel<true><<<g64, 256, 0, stream>>>(feat, W1h, as1, ad1, hh, asr, adt, N);
    message128_kernel<<<(N + 7) / 8, 256, 0, stream>>>((const uint4*)hh, row_ptr, srcs, asr, adt,
                                                       b1, g1, bb1, m1, v1, feat, N);
    // layer 2: feat -> d_out
    gemm40_mfma_kernel<<<g64, 256, 0, stream>>>(feat, W2h, as2, ad2, h2, asr, adt, N);
    message40_kernel<<<(N + 15) / 16, 256, 0, stream>>>((const uint2*)h2, row_ptr, srcs,
                                                        asr, adt, b2, (float*)d_out, N);
}

// Round 11
// 209.690 us; speedup vs baseline: 1.1289x; 1.1289x over previous
//
#include <hip/hip_runtime.h>
#include <hip/hip_fp16.h>
#include <math.h>

constexpr float NEG_SLOPE = 0.2f;
constexpr float BN_EPS_C = 1e-5f;

using half8 = __attribute__((ext_vector_type(8))) _Float16;
using f32x4 = __attribute__((ext_vector_type(4))) float;

// ================= weight fp16 pre-conversion =================

__global__ void cvt_w_kernel(const float* __restrict__ W0, const float* __restrict__ W1,
                             const float* __restrict__ W2,
                             __half* __restrict__ W0h, __half* __restrict__ W1h,
                             __half* __restrict__ W2h) {
    int i = blockIdx.x * blockDim.x + threadIdx.x;
    if (i < 16384) {
        W0h[i] = __float2half(W0[i]);
        W1h[i] = __float2half(W1[i]);
    }
    if (i < 6144) W2h[i] = __float2half(i < 5120 ? W2[i] : 0.f);  // pad rows 40..47 = 0
}

// ================= CSR build: LDS-binned two-level counting sort =================

__global__ __launch_bounds__(256)
void bucket_hist_kernel(const int* __restrict__ ei, int* __restrict__ bucket_count,
                        int E, int N) {
    __shared__ int h[256];
    int t = threadIdx.x;
    h[t] = 0;
    __syncthreads();
    int base = blockIdx.x * 4096;
    int ET = E + N;
#pragma unroll
    for (int q = 0; q < 16; ++q) {
        int i = base + q * 256 + t;
        if (i < ET) {
            int d = (i < E) ? ei[E + i] : (i - E);
            atomicAdd(&h[d >> 8], 1);
        }
    }
    __syncthreads();
    if (h[t] > 0) atomicAdd(&bucket_count[t], h[t]);
}

__global__ __launch_bounds__(256)
void bucket_scan_kernel(const int* __restrict__ bucket_count, int* __restrict__ bucket_ptr,
                        int* __restrict__ gcursor, int* __restrict__ row_ptr,
                        int N, int ET) {
    __shared__ int s[256];
    int t = threadIdx.x;
    int c = bucket_count[t];
    s[t] = c;
    __syncthreads();
    for (int off = 1; off < 256; off <<= 1) {
        int v = (t >= off) ? s[t - off] : 0;
        __syncthreads();
        s[t] += v;
        __syncthreads();
    }
    int excl = s[t] - c;
    bucket_ptr[t] = excl;
    gcursor[t] = excl;
    if (t == 255) {
        bucket_ptr[256] = s[255];
        row_ptr[N] = ET;
    }
}

__global__ __launch_bounds__(256)
void bucket_bin_kernel(const int* __restrict__ ei, int* __restrict__ gcursor,
                       int2* __restrict__ tmp, int E, int N) {
    __shared__ int2 bins[4096];
    __shared__ int lcount[256];
    __shared__ int lofs[256];
    __shared__ int lbase[256];
    __shared__ int lcur[256];
    int t = threadIdx.x;
    lcount[t] = 0;
    __syncthreads();
    int base = blockIdx.x * 4096;
    int ET = E + N;
    int2 pr[16];
#pragma unroll
    for (int q = 0; q < 16; ++q) {
        int i = base + q * 256 + t;
        pr[q] = make_int2(-1, -1);
        if (i < ET) {
            int s, d;
            if (i < E) { s = ei[i]; d = ei[E + i]; }
            else       { s = i - E; d = s; }
            pr[q] = make_int2(d, s);
            atomicAdd(&lcount[d >> 8], 1);
        }
    }
    __syncthreads();
    {
        int c = lcount[t];
        lofs[t] = c;
        __syncthreads();
        for (int off = 1; off < 256; off <<= 1) {
            int v = (t >= off) ? lofs[t - off] : 0;
            __syncthreads();
            lofs[t] += v;
            __syncthreads();
        }
        int excl = lofs[t] - c;
        __syncthreads();
        lofs[t] = excl;
        lcur[t] = excl;
        if (c > 0) lbase[t] = atomicAdd(&gcursor[t], c);
    }
    __syncthreads();
#pragma unroll
    for (int q = 0; q < 16; ++q) {
        if (pr[q].x >= 0) {
            int b = pr[q].x >> 8;
            int p = atomicAdd(&lcur[b], 1);
            bins[p] = pr[q];
        }
    }
    __syncthreads();
    int total = min(4096, ET - base);
    for (int p = t; p < total; p += 256) {
        int2 e = bins[p];
        int b = e.x >> 8;
        tmp[lbase[b] + (p - lofs[b])] = e;
    }
}

__global__ __launch_bounds__(256)
void fine_scatter_kernel(const int2* __restrict__ tmp, const int* __restrict__ bucket_ptr,
                         int* __restrict__ row_ptr, int* __restrict__ srcs, int N) {
    __shared__ int hist[256];
    __shared__ int scanb[256];
    __shared__ int cur[256];
    int b = blockIdx.x, t = threadIdx.x;
    int base = bucket_ptr[b];
    int cnt = bucket_ptr[b + 1] - base;
    int n0 = b << 8;
    hist[t] = 0;
    __syncthreads();
    for (int p = t; p < cnt; p += 256)
        atomicAdd(&hist[tmp[base + p].x - n0], 1);
    __syncthreads();
    int c = hist[t];
    scanb[t] = c;
    __syncthreads();
    for (int off = 1; off < 256; off <<= 1) {
        int v = (t >= off) ? scanb[t - off] : 0;
        __syncthreads();
        scanb[t] += v;
        __syncthreads();
    }
    int excl = scanb[t] - c;
    cur[t] = excl;
    if (n0 + t < N) row_ptr[n0 + t] = base + excl;
    __syncthreads();
    for (int p = t; p < cnt; p += 256) {
        int2 e = tmp[base + p];
        int pos = atomicAdd(&cur[e.x - n0], 1);
        srcs[base + pos] = e.y;
    }
}

// ---------------- MFMA GEMM 128 (W in LDS, A direct): h(fp16) = X @ W^T + alphas ----------
// Block = 256 threads = 4 waves, 64 rows. B staged in LDS (fp16 memcpy, no cvt).
// C/D: col=lane&15, row=(lane>>4)*4+reg (verified rounds 6-9).

template<bool AHALF>
__global__ __launch_bounds__(256)
void gemm128_mfma_kernel(const void* __restrict__ Xv, const __half* __restrict__ W16,
                         const float* __restrict__ a_src, const float* __restrict__ a_dst,
                         __half* __restrict__ hp, float* __restrict__ asrc,
                         float* __restrict__ adst, int N) {
    __shared__ _Float16 Bs[128][136];
    const int t = threadIdx.x;
    const int n0 = blockIdx.x * 64;

    // stage W (fp16, straight uint4 copy): 128 rows x 16 chunks of 8 halves
#pragma unroll
    for (int i = 0; i < 8; ++i) {
        int lin = t + i * 256;
        int n = lin >> 4;        // 0..127
        int m = lin & 15;        // 0..15 (8-half chunk)
        *reinterpret_cast<uint4*>(&Bs[n][8 * m]) =
            *reinterpret_cast<const uint4*>(&W16[(size_t)n * 128 + 8 * m]);
    }
    __syncthreads();

    const int l  = t & 63;
    const int w  = t >> 6;
    const int lr = l & 15;
    const int lg = l >> 4;
    const int rowA = n0 + 16 * w + lr;
    const bool rokA = rowA < N;

    f32x4 acc[8];
#pragma unroll
    for (int tt = 0; tt < 8; ++tt) acc[tt] = (f32x4){0.f, 0.f, 0.f, 0.f};

#pragma unroll
    for (int ks = 0; ks < 4; ++ks) {
        half8 a;
        if (rokA) {
            if constexpr (AHALF) {
                const __half* X = (const __half*)Xv;
                a = *reinterpret_cast<const half8*>(&X[(size_t)rowA * 128 + 8 * lg + 32 * ks]);
            } else {
                const float* X = (const float*)Xv;
                const float* p = &X[(size_t)rowA * 128 + 8 * lg + 32 * ks];
                float4 v0 = *reinterpret_cast<const float4*>(p);
                float4 v1 = *reinterpret_cast<const float4*>(p + 4);
                a[0] = (_Float16)v0.x; a[1] = (_Float16)v0.y;
                a[2] = (_Float16)v0.z; a[3] = (_Float16)v0.w;
                a[4] = (_Float16)v1.x; a[5] = (_Float16)v1.y;
                a[6] = (_Float16)v1.z; a[7] = (_Float16)v1.w;
            }
        } else {
#pragma unroll
            for (int q = 0; q < 8; ++q) a[q] = (_Float16)0.f;
        }
#pragma unroll
        for (int tt = 0; tt < 8; ++tt) {
            half8 b = *reinterpret_cast<const half8*>(&Bs[16 * tt + lr][8 * lg + 32 * ks]);
            acc[tt] = __builtin_amdgcn_mfma_f32_16x16x32_f16(a, b, acc[tt], 0, 0, 0);
        }
    }

    float av[8], bv[8];
#pragma unroll
    for (int tt = 0; tt < 8; ++tt) {
        av[tt] = a_src[16 * tt + lr];
        bv[tt] = a_dst[16 * tt + lr];
    }
#pragma unroll
    for (int reg = 0; reg < 4; ++reg) {
        int gr = n0 + 16 * w + 4 * lg + reg;
        bool ok = gr < N;
        if (ok) {
#pragma unroll
            for (int tt = 0; tt < 8; ++tt)
                hp[(size_t)gr * 128 + 16 * tt + lr] = __float2half(acc[tt][reg]);
        }
#pragma unroll
        for (int tt = 0; tt < 8; ++tt) {
            float p = acc[tt][reg] * av[tt];
            float q = acc[tt][reg] * bv[tt];
#pragma unroll
            for (int off = 1; off < 16; off <<= 1) {
                p += __shfl_xor(p, off, 16);
                q += __shfl_xor(q, off, 16);
            }
            if (ok && lr == tt) {
                asrc[(size_t)gr * 8 + tt] = p;
                adst[(size_t)gr * 8 + tt] = q;
            }
        }
    }
}

// ---------------- MFMA GEMM 40 (W in LDS, A direct): h2(fp16) = feat @ W2^T + alphas -------

__global__ __launch_bounds__(256)
void gemm40_mfma_kernel(const __half* __restrict__ X, const __half* __restrict__ W16,
                        const float* __restrict__ a_src, const float* __restrict__ a_dst,
                        __half* __restrict__ hp, float* __restrict__ asrc,
                        float* __restrict__ adst, int N) {
    __shared__ _Float16 Bs[48][136];
    const int t = threadIdx.x;
    const int n0 = blockIdx.x * 64;

#pragma unroll
    for (int i = 0; i < 3; ++i) {
        int lin = t + i * 256;
        if (lin < 768) {
            int n = lin >> 4;
            int m = lin & 15;    // 8-half chunk
            *reinterpret_cast<uint4*>(&Bs[n][8 * m]) =
                *reinterpret_cast<const uint4*>(&W16[(size_t)n * 128 + 8 * m]);
        }
    }
    __syncthreads();

    const int l  = t & 63;
    const int w  = t >> 6;
    const int lr = l & 15;
    const int lg = l >> 4;
    const int rowA = n0 + 16 * w + lr;
    const bool rokA = rowA < N;

    f32x4 acc[3];
#pragma unroll
    for (int tt = 0; tt < 3; ++tt) acc[tt] = (f32x4){0.f, 0.f, 0.f, 0.f};

#pragma unroll
    for (int ks = 0; ks < 4; ++ks) {
        half8 a;
        if (rokA) {
            a = *reinterpret_cast<const half8*>(&X[(size_t)rowA * 128 + 8 * lg + 32 * ks]);
        } else {
#pragma unroll
            for (int q = 0; q < 8; ++q) a[q] = (_Float16)0.f;
        }
#pragma unroll
        for (int tt = 0; tt < 3; ++tt) {
            half8 b = *reinterpret_cast<const half8*>(&Bs[16 * tt + lr][8 * lg + 32 * ks]);
            acc[tt] = __builtin_amdgcn_mfma_f32_16x16x32_f16(a, b, acc[tt], 0, 0, 0);
        }
    }

    float av[3], bv[3];
#pragma unroll
    for (int tt = 0; tt < 3; ++tt) {
        int j = 16 * tt + lr;
        av[tt] = (j < 40) ? a_src[j] : 0.f;
        bv[tt] = (j < 40) ? a_dst[j] : 0.f;
    }
#pragma unroll
    for (int reg = 0; reg < 4; ++reg) {
        int gr = n0 + 16 * w + 4 * lg + reg;
        bool ok = gr < N;
        float p = 0.f, q = 0.f;
#pragma unroll
        for (int tt = 0; tt < 3; ++tt) {
            int j = 16 * tt + lr;
            if (ok && j < 40) hp[(size_t)gr * 40 + j] = __float2half(acc[tt][reg]);
            p += acc[tt][reg] * av[tt];
            q += acc[tt][reg] * bv[tt];
        }
#pragma unroll
        for (int off = 1; off < 16; off <<= 1) {
            p += __shfl_xor(p, off, 16);
            q += __shfl_xor(q, off, 16);
        }
        if (ok && lr == 0) {
            asrc[gr] = p;
            adst[gr] = q;
        }
    }
}

// ---------------- fused message + softmax, F=128, H=8, fp16 out ----------------
// 32 lanes/node; 16 lanes/edge, up to 4 edges in flight (2 per half).

__global__ __launch_bounds__(256)
void message128_kernel(const uint4* __restrict__ hh4, const int* __restrict__ row_ptr,
                       const int* __restrict__ srcs,
                       const float* __restrict__ asrc, const float* __restrict__ adst,
                       const float* __restrict__ bias,
                       const float* __restrict__ bn_g, const float* __restrict__ bn_b,
                       const float* __restrict__ bn_m, const float* __restrict__ bn_v,
                       __half* __restrict__ out16, int N) {
    int node = blockIdx.x * 8 + (threadIdx.x >> 5);
    if (node >= N) return;
    int tc = threadIdx.x & 31;
    int half_id = tc >> 4;
    int cl = tc & 15;
    int hd = cl >> 1;
    int beg = row_ptr[node], end = row_ptr[node + 1];
    float ad = adst[(size_t)node * 8 + hd];
    float ssum = 0.f;
    float acc[8];
#pragma unroll
    for (int q = 0; q < 8; ++q) acc[q] = 0.f;

    int j = beg;
    for (; j + 4 <= end; j += 4) {
        int sA = srcs[j + half_id];
        int sB = srcs[j + 2 + half_id];
        uint4 uA = hh4[(size_t)sA * 16 + cl];
        uint4 uB = hh4[(size_t)sB * 16 + cl];
        float eA = asrc[(size_t)sA * 8 + hd] + ad;
        float eB = asrc[(size_t)sB * 8 + hd] + ad;
        eA = (eA > 0.f) ? eA : NEG_SLOPE * eA;
        eB = (eB > 0.f) ? eB : NEG_SLOPE * eB;
        float wA = __expf(eA);
        float wB = __expf(eB);
        ssum += wA + wB;
        float2 a0 = __half22float2(*reinterpret_cast<const __half2*>(&uA.x));
        float2 a1 = __half22float2(*reinterpret_cast<const __half2*>(&uA.y));
        float2 a2 = __half22float2(*reinterpret_cast<const __half2*>(&uA.z));
        float2 a3 = __half22float2(*reinterpret_cast<const __half2*>(&uA.w));
        float2 b0 = __half22float2(*reinterpret_cast<const __half2*>(&uB.x));
        float2 b1 = __half22float2(*reinterpret_cast<const __half2*>(&uB.y));
        float2 b2 = __half22float2(*reinterpret_cast<const __half2*>(&uB.z));
        float2 b3 = __half22float2(*reinterpret_cast<const __half2*>(&uB.w));
        acc[0] += wA * a0.x + wB * b0.x; acc[1] += wA * a0.y + wB * b0.y;
        acc[2] += wA * a1.x + wB * b1.x; acc[3] += wA * a1.y + wB * b1.y;
        acc[4] += wA * a2.x + wB * b2.x; acc[5] += wA * a2.y + wB * b2.y;
        acc[6] += wA * a3.x + wB * b3.x; acc[7] += wA * a3.y + wB * b3.y;
    }
    for (; j + 2 <= end; j += 2) {
        int s = srcs[j + half_id];
        uint4 u = hh4[(size_t)s * 16 + cl];
        float e = asrc[(size_t)s * 8 + hd] + ad;
        e = (e > 0.f) ? e : NEG_SLOPE * e;
        float wgt = __expf(e);
        ssum += wgt;
        float2 f0 = __half22float2(*reinterpret_cast<const __half2*>(&u.x));
        float2 f1 = __half22float2(*reinterpret_cast<const __half2*>(&u.y));
        float2 f2 = __half22float2(*reinterpret_cast<const __half2*>(&u.z));
        float2 f3 = __half22float2(*reinterpret_cast<const __half2*>(&u.w));
        acc[0] += wgt * f0.x; acc[1] += wgt * f0.y;
        acc[2] += wgt * f1.x; acc[3] += wgt * f1.y;
        acc[4] += wgt * f2.x; acc[5] += wgt * f2.y;
        acc[6] += wgt * f3.x; acc[7] += wgt * f3.y;
    }
    if (j < end && half_id == 0) {
        int s = srcs[j];
        uint4 u = hh4[(size_t)s * 16 + cl];
        float e = asrc[(size_t)s * 8 + hd] + ad;
        e = (e > 0.f) ? e : NEG_SLOPE * e;
        float wgt = __expf(e);
        ssum += wgt;
        float2 f0 = __half22float2(*reinterpret_cast<const __half2*>(&u.x));
        float2 f1 = __half22float2(*reinterpret_cast<const __half2*>(&u.y));
        float2 f2 = __half22float2(*reinterpret_cast<const __half2*>(&u.z));
        float2 f3 = __half22float2(*reinterpret_cast<const __half2*>(&u.w));
        acc[0] += wgt * f0.x; acc[1] += wgt * f0.y;
        acc[2] += wgt * f1.x; acc[3] += wgt * f1.y;
        acc[4] += wgt * f2.x; acc[5] += wgt * f2.y;
        acc[6] += wgt * f3.x; acc[7] += wgt * f3.y;
    }
    ssum += __shfl_xor(ssum, 16);
#pragma unroll
    for (int q = 0; q < 8; ++q) acc[q] += __shfl_xor(acc[q], 16);

    if (half_id == 0) {
        float inv = 1.0f / (ssum + 1e-16f);
        int c = cl * 8;
        float r[8];
#pragma unroll
        for (int pp = 0; pp < 2; ++pp) {
            int cc = c + 4 * pp;
            float4 bi = *reinterpret_cast<const float4*>(&bias[cc]);
            float4 g  = *reinterpret_cast<const float4*>(&bn_g[cc]);
            float4 bb = *reinterpret_cast<const float4*>(&bn_b[cc]);
            float4 mm = *reinterpret_cast<const float4*>(&bn_m[cc]);
            float4 vv = *reinterpret_cast<const float4*>(&bn_v[cc]);
            r[4 * pp + 0] = (acc[4 * pp + 0] * inv + bi.x - mm.x) * rsqrtf(vv.x + BN_EPS_C) * g.x + bb.x;
            r[4 * pp + 1] = (acc[4 * pp + 1] * inv + bi.y - mm.y) * rsqrtf(vv.y + BN_EPS_C) * g.y + bb.y;
            r[4 * pp + 2] = (acc[4 * pp + 2] * inv + bi.z - mm.z) * rsqrtf(vv.z + BN_EPS_C) * g.z + bb.z;
            r[4 * pp + 3] = (acc[4 * pp + 3] * inv + bi.w - mm.w) * rsqrtf(vv.w + BN_EPS_C) * g.w + bb.w;
        }
        half8 o;
#pragma unroll
        for (int q = 0; q < 8; ++q) {
            float rv = (r[q] > 0.f) ? r[q] : expm1f(r[q]);
            o[q] = (_Float16)rv;
        }
        *reinterpret_cast<half8*>(&out16[(size_t)node * 128 + c]) = o;
    }
}

// ---------------- fused message + softmax, F=40, H=1, fp16 gather ----------------

__global__ __launch_bounds__(256)
void message40_kernel(const uint2* __restrict__ hh2, const int* __restrict__ row_ptr,
                      const int* __restrict__ srcs,
                      const float* __restrict__ asrc, const float* __restrict__ adst,
                      const float* __restrict__ b2, float* __restrict__ out, int N) {
    int node = blockIdx.x * 16 + (threadIdx.x >> 4);
    if (node >= N) return;
    int tc = threadIdx.x & 15;
    int beg = row_ptr[node], end = row_ptr[node + 1];
    float ad = adst[node];
    float ssum = 0.f;
    float4 acc = make_float4(0.f, 0.f, 0.f, 0.f);
    int j = beg;
    for (; j + 2 <= end; j += 2) {
        int s0 = srcs[j];
        int s1 = srcs[j + 1];
        uint2 u0 = make_uint2(0u, 0u), u1 = make_uint2(0u, 0u);
        if (tc < 10) {
            u0 = hh2[(size_t)s0 * 10 + tc];
            u1 = hh2[(size_t)s1 * 10 + tc];
        }
        float e0 = asrc[s0] + ad;
        float e1 = asrc[s1] + ad;
        e0 = (e0 > 0.f) ? e0 : NEG_SLOPE * e0;
        e1 = (e1 > 0.f) ? e1 : NEG_SLOPE * e1;
        float w0 = __expf(e0);
        float w1 = __expf(e1);
        ssum += w0 + w1;
        float2 a0 = __half22float2(*reinterpret_cast<const __half2*>(&u0.x));
        float2 b0 = __half22float2(*reinterpret_cast<const __half2*>(&u0.y));
        float2 a1 = __half22float2(*reinterpret_cast<const __half2*>(&u1.x));
        float2 b1 = __half22float2(*reinterpret_cast<const __half2*>(&u1.y));
        acc.x += w0 * a0.x + w1 * a1.x;
        acc.y += w0 * a0.y + w1 * a1.y;
        acc.z += w0 * b0.x + w1 * b1.x;
        acc.w += w0 * b0.y + w1 * b1.y;
    }
    if (j < end) {
        int s0 = srcs[j];
        uint2 u0 = make_uint2(0u, 0u);
        if (tc < 10) u0 = hh2[(size_t)s0 * 10 + tc];
        float e0 = asrc[s0] + ad;
        e0 = (e0 > 0.f) ? e0 : NEG_SLOPE * e0;
        float w0 = __expf(e0);
        ssum += w0;
        float2 a0 = __half22float2(*reinterpret_cast<const __half2*>(&u0.x));
        float2 b0 = __half22float2(*reinterpret_cast<const __half2*>(&u0.y));
        acc.x += w0 * a0.x;
        acc.y += w0 * a0.y;
        acc.z += w0 * b0.x;
        acc.w += w0 * b0.y;
    }
    if (tc < 10) {
        float inv = 1.0f / (ssum + 1e-16f);
        int c = tc * 4;
        float4 bi = *reinterpret_cast<const float4*>(&b2[c]);
        *reinterpret_cast<float4*>(&out[(size_t)node * 40 + c]) =
            make_float4(acc.x * inv + bi.x, acc.y * inv + bi.y,
                        acc.z * inv + bi.z, acc.w * inv + bi.w);
    }
}

// ---------------- launcher ----------------

static inline char* align256(char* p) {
    return (char*)(((uintptr_t)p + 255) & ~(uintptr_t)255);
}

extern "C" void kernel_launch(void* const* d_in, const int* in_sizes, int n_in,
                              void* d_out, int out_size, void* d_ws, size_t ws_size,
                              hipStream_t stream) {
    const float* x   = (const float*)d_in[0];
    const int*   ei  = (const int*)d_in[1];
    const float* W0  = (const float*)d_in[2];
    const float* as0 = (const float*)d_in[3];
    const float* ad0 = (const float*)d_in[4];
    const float* b0  = (const float*)d_in[5];
    const float* g0  = (const float*)d_in[6];
    const float* bb0 = (const float*)d_in[7];
    const float* m0  = (const float*)d_in[8];
    const float* v0  = (const float*)d_in[9];
    const float* W1  = (const float*)d_in[10];
    const float* as1 = (const float*)d_in[11];
    const float* ad1 = (const float*)d_in[12];
    const float* b1  = (const float*)d_in[13];
    const float* g1  = (const float*)d_in[14];
    const float* bb1 = (const float*)d_in[15];
    const float* m1  = (const float*)d_in[16];
    const float* v1  = (const float*)d_in[17];
    const float* W2  = (const float*)d_in[18];
    const float* as2 = (const float*)d_in[19];
    const float* ad2 = (const float*)d_in[20];
    const float* b2  = (const float*)d_in[21];

    const int N  = in_sizes[0] / 128;
    const int E  = in_sizes[1] / 2;
    const int ET = E + N;
    const int NBUK = (N + 255) >> 8;
    const int NEB  = (ET + 4095) / 4096;

    char* wsp = (char*)d_ws;
    int* bucket_count = (int*)wsp;  wsp = align256(wsp + 256 * 4);
    int* bucket_ptr   = (int*)wsp;  wsp = align256(wsp + 257 * 4);
    int* gcursor      = (int*)wsp;  wsp = align256(wsp + 256 * 4);
    int* row_ptr      = (int*)wsp;  wsp = align256(wsp + (size_t)(N + 1) * 4);
    int2* tmp         = (int2*)wsp; wsp = align256(wsp + (size_t)ET * 8);
    int* srcs         = (int*)wsp;  wsp = align256(wsp + (size_t)ET * 4);
    __half* hh        = (__half*)wsp; wsp = align256(wsp + (size_t)N * 128 * 2);
    __half* h2        = (__half*)wsp; wsp = align256(wsp + (size_t)N * 40 * 2);
    __half* feat      = (__half*)wsp; wsp = align256(wsp + (size_t)N * 128 * 2);
    float* asr        = (float*)wsp;  wsp = align256(wsp + (size_t)N * 8 * 4);
    float* adt        = (float*)wsp;  wsp = align256(wsp + (size_t)N * 8 * 4);
    __half* W0h       = (__half*)wsp; wsp = align256(wsp + 16384 * 2);
    __half* W1h       = (__half*)wsp; wsp = align256(wsp + 16384 * 2);
    __half* W2h       = (__half*)wsp; wsp = align256(wsp + 6144 * 2);

    // weight fp16 pre-conversion (once)
    cvt_w_kernel<<<64, 256, 0, stream>>>(W0, W1, W2, W0h, W1h, W2h);

    // CSR build (LDS-binned two-level counting sort)
    hipMemsetAsync(bucket_count, 0, 256 * 4, stream);
    bucket_hist_kernel<<<NEB, 256, 0, stream>>>(ei, bucket_count, E, N);
    bucket_scan_kernel<<<1, 256, 0, stream>>>(bucket_count, bucket_ptr, gcursor, row_ptr, N, ET);
    bucket_bin_kernel<<<NEB, 256, 0, stream>>>(ei, gcursor, tmp, E, N);
    fine_scatter_kernel<<<NBUK, 256, 0, stream>>>(tmp, bucket_ptr, row_ptr, srcs, N);

    const int g64 = (N + 63) / 64;

    // layer 0: x (fp32) -> feat (fp16)
    gemm128_mfma_kernel<false><<<g64, 256, 0, stream>>>(x, W0h, as0, ad0, hh, asr, adt, N);
    message128_kernel<<<(N + 7) / 8, 256, 0, stream>>>((const uint4*)hh, row_ptr, srcs, asr, adt,
                                                       b0, g0, bb0, m0, v0, feat, N);
    // layer 1: feat (fp16) -> feat (fp16)
    gemm128_mfma_kernel<true><<<g64, 256, 0, stream>>>(feat, W1h, as1, ad1, hh, asr, adt, N);
    message128_kernel<<<(N + 7) / 8, 256, 0, stream>>>((const uint4*)hh, row_ptr, srcs, asr, adt,
                                                       b1, g1, bb1, m1, v1, feat, N);
    // layer 2: feat -> d_out
    gemm40_mfma_kernel<<<g64, 256, 0, stream>>>(feat, W2h, as2, ad2, h2, asr, adt, N);
    message40_kernel<<<(N + 15) / 16, 256, 0, stream>>>((const uint2*)h2, row_ptr, srcs,
                                                        asr, adt, b2, (float*)d_out, N);
}